// Round 17
// baseline (171.183 us; speedup 1.0000x reference)
//
#include <hip/hip_runtime.h>

#define DIN 128
#define DHID 128
#define DOUT 64
#define CAPB 6144    // bin capacity per 256-node range (mean ~4082, sigma ~64)
#define CHUNK 4096   // edges per binA block
#define EPT (CHUNK / 256)

typedef short bf16x8 __attribute__((ext_vector_type(8)));
typedef float f32x4 __attribute__((ext_vector_type(4)));

// ---- bf16 helpers ---------------------------------------------------------
static __device__ __forceinline__ unsigned short f2bf(float f) {
  union { float f; unsigned u; } v; v.f = f;
  unsigned r = v.u + 0x7fffu + ((v.u >> 16) & 1u);  // round-nearest-even
  return (unsigned short)(r >> 16);
}
static __device__ __forceinline__ float bf_lo(unsigned v) {
  union { unsigned u; float f; } t; t.u = v << 16; return t.f;
}
static __device__ __forceinline__ float bf_hi(unsigned v) {
  union { unsigned u; float f; } t; t.u = v & 0xffff0000u; return t.f;
}

// ---------------------------------------------------------------------------
// init: zero bincursor + frag-order bf16 conversion of W1/W2 (one launch).
// ---------------------------------------------------------------------------
static __device__ __forceinline__ void wcast_body(
    const float* __restrict__ W, unsigned short* __restrict__ Wf,
    int NOUT, int tid) {
  int f = tid >> 6;
  int lane = tid & 63;
  int t = f & 3;
  int nt = f >> 2;
  int kbase = t * 32 + (lane >> 4) * 8;
  int n = nt * 16 + (lane & 15);
#pragma unroll
  for (int j = 0; j < 8; ++j)
    Wf[(size_t)tid * 8 + j] = f2bf(W[(size_t)(kbase + j) * NOUT + n]);
}

__global__ __launch_bounds__(256) void init_kernel(
    const float* __restrict__ W1, const float* __restrict__ W2,
    unsigned short* __restrict__ Wf1, unsigned short* __restrict__ Wf2,
    int* __restrict__ bincursor) {
  const int b = blockIdx.x;
  const int t = threadIdx.x;
  if (b == 0) {
    bincursor[t] = 0;
  } else if (b <= 8) {
    wcast_body(W1, Wf1, DHID, (b - 1) * 256 + t);
  } else {
    wcast_body(W2, Wf2, DOUT, (b - 9) * 256 + t);
  }
}

// ---------------------------------------------------------------------------
// gemm1 tile: 64 rows of C[M,128](bf16) = A[M,128](fp32) * Wf1 (regs).
// ---------------------------------------------------------------------------
static __device__ void gemm1_tile(
    const float* __restrict__ A, const unsigned short* __restrict__ Wf,
    unsigned short* __restrict__ C, int M, int tile) {
  constexpr int NT = DHID / 16;  // 8
  const int lane = threadIdx.x & 63;
  const int wave = threadIdx.x >> 6;
  const int g = lane >> 4;
  const int m15 = lane & 15;

  bf16x8 bfrag[NT * 4];
#pragma unroll
  for (int f = 0; f < NT * 4; ++f)
    bfrag[f] = *(const bf16x8*)(Wf + ((size_t)(f * 64 + lane)) * 8);

  const int rowbase = tile * 64 + wave * 16;
  if (rowbase >= M) return;
  f32x4 acc[NT];
#pragma unroll
  for (int nt = 0; nt < NT; ++nt) acc[nt] = (f32x4){0.f, 0.f, 0.f, 0.f};
  const float* arow = A + (size_t)(rowbase + m15) * 128 + g * 8;
  bf16x8 af[4];
#pragma unroll
  for (int t = 0; t < 4; ++t) {
    float4 a0 = *(const float4*)(arow + t * 32);
    float4 a1 = *(const float4*)(arow + t * 32 + 4);
    bf16x8 f;
    f[0] = (short)f2bf(a0.x); f[1] = (short)f2bf(a0.y);
    f[2] = (short)f2bf(a0.z); f[3] = (short)f2bf(a0.w);
    f[4] = (short)f2bf(a1.x); f[5] = (short)f2bf(a1.y);
    f[6] = (short)f2bf(a1.z); f[7] = (short)f2bf(a1.w);
    af[t] = f;
  }
#pragma unroll
  for (int t = 0; t < 4; ++t)
#pragma unroll
    for (int nt = 0; nt < NT; ++nt)
      acc[nt] = __builtin_amdgcn_mfma_f32_16x16x32_bf16(
          af[t], bfrag[nt * 4 + t], acc[nt], 0, 0, 0);
#pragma unroll
  for (int nt = 0; nt < NT; ++nt)
#pragma unroll
    for (int r = 0; r < 4; ++r) {
      int row = rowbase + g * 4 + r;
      if (row < M)
        C[(size_t)row * DHID + nt * 16 + m15] = f2bf(acc[nt][r]);
    }
}

// ---------------------------------------------------------------------------
// phaseA: blocks [0,nbinA) bin edges by range (LDS, burst writes); blocks
// [nbinA, ...) each run one gemm1 tile (independent -> overlap).
// ---------------------------------------------------------------------------
__global__ __launch_bounds__(256) void phaseA_kernel(
    const int* __restrict__ src, const int* __restrict__ dst,
    int* __restrict__ bincursor, unsigned* __restrict__ binbuf, int E,
    int nbinA, const float* __restrict__ x,
    const unsigned short* __restrict__ Wf1, unsigned short* __restrict__ h1,
    int M) {
  __shared__ int hist[256];
  __shared__ int cnt[256];
  __shared__ int offs[256];
  __shared__ int cur[256];
  __shared__ int gbase[256];
  __shared__ unsigned stage[CHUNK];

  if ((int)blockIdx.x >= nbinA) {
    gemm1_tile(x, Wf1, h1, M, (int)blockIdx.x - nbinA);
    return;
  }

  const int t = threadIdx.x;
  const int base = blockIdx.x * CHUNK;
  const int n = min(CHUNK, E - base);

  hist[t] = 0;
  __syncthreads();

  unsigned rec[EPT];
  int rng[EPT];
#pragma unroll
  for (int j = 0; j < EPT; ++j) {
    int e = base + j * 256 + t;
    rng[j] = -1;
    if (e < E) {
      int d = dst[e];
      int s = src[e];
      int r = d >> 8;
      rng[j] = r;
      rec[j] = (unsigned)s | ((unsigned)(d & 255) << 16) | ((unsigned)r << 24);
      atomicAdd(&hist[r], 1);
    }
  }
  __syncthreads();
  int myc = hist[t];
  cnt[t] = myc;
  __syncthreads();
#pragma unroll
  for (int o = 1; o < 256; o <<= 1) {
    int u = (t >= o) ? hist[t - o] : 0;
    __syncthreads();
    hist[t] += u;
    __syncthreads();
  }
  offs[t] = hist[t] - myc;
  cur[t] = hist[t] - myc;
  __syncthreads();
#pragma unroll
  for (int j = 0; j < EPT; ++j) {
    if (rng[j] >= 0) {
      int pos = atomicAdd(&cur[rng[j]], 1);
      stage[pos] = rec[j];
    }
  }
  __syncthreads();
  int c = cnt[t];
  gbase[t] = c ? atomicAdd(&bincursor[t], c) : 0;
  __syncthreads();
  for (int i = t; i < n; i += 256) {
    unsigned v = stage[i];
    int r = v >> 24;
    int local = i - offs[r];
    int gpos = gbase[r] + local;
    if (gpos < CAPB) binbuf[(size_t)r * CAPB + gpos] = v & 0x00ffffffu;
  }
}

// ---------------------------------------------------------------------------
// scan_local: block b histograms its range's bin segment -> deg, fuses dinv,
// local exclusive scan -> rowrange[i] = (start, end) LOCAL to the range.
// ---------------------------------------------------------------------------
__global__ __launch_bounds__(256) void scan_local_kernel(
    const unsigned* __restrict__ binbuf, const int* __restrict__ bincursor,
    int2* __restrict__ rowrange, float* __restrict__ dinv, int n) {
  __shared__ int deg[256];
  __shared__ int lds[256];
  const int t = threadIdx.x;
  const int b = blockIdx.x;
  deg[t] = 0;
  __syncthreads();
  const int cnt = min(bincursor[b], CAPB);
  const unsigned* seg = binbuf + (size_t)b * CAPB;
  for (int i = t; i < cnt; i += 256) atomicAdd(&deg[(seg[i] >> 16) & 0xff], 1);
  __syncthreads();
  const int i = b * 256 + t;
  int v = deg[t];
  if (i < n) dinv[i] = rsqrtf((float)v + 1.0f);
  lds[t] = v;
  __syncthreads();
#pragma unroll
  for (int o = 1; o < 256; o <<= 1) {
    int u = (t >= o) ? lds[t - o] : 0;
    __syncthreads();
    lds[t] += u;
    __syncthreads();
  }
  if (i < n) rowrange[i] = make_int2(lds[t] - v, lds[t]);
}

// ---------------------------------------------------------------------------
// binB: one block per range; reads its contiguous bin segment, computes
// weights (dinv L2-hot), places recs (src | bf16(w)<<16) via LDS cursors,
// writes back IN-PLACE (recs aliases binbuf: all global reads of the
// segment complete before the post-sync writes).
// ---------------------------------------------------------------------------
__global__ __launch_bounds__(256) void binB_kernel(
    unsigned* __restrict__ binbuf, const int* __restrict__ bincursor,
    const int2* __restrict__ rowrange, const float* __restrict__ dinv,
    int n) {
  __shared__ int curs[256];
  __shared__ unsigned stage[CAPB];
  const int t = threadIdx.x;
  const int r = blockIdx.x;
  const int n0 = r * 256;
  curs[t] = (n0 + t < n) ? rowrange[n0 + t].x : 0;
  __syncthreads();
  const int cnt = min(bincursor[r], CAPB);
  unsigned* seg = binbuf + (size_t)r * CAPB;
  for (int i = t; i < cnt; i += 256) {
    unsigned v = seg[i];
    int s = v & 0xffffu;
    int dl = (v >> 16) & 0xff;
    float w = dinv[s] * dinv[n0 + dl];
    int pos = atomicAdd(&curs[dl], 1);
    stage[pos] = (unsigned)s | ((unsigned)f2bf(w) << 16);
  }
  __syncthreads();
  for (int i = t; i < cnt; i += 256) seg[i] = stage[i];
}

// ---------------------------------------------------------------------------
// agg1_gemm2: block = 16 nodes, wave = 4 nodes. QUARTER-WAVE gather (each
// 16-lane quarter fetches one edge's 256B h1 row as uint4, 4 edges/j-step).
// NEW: full 16-edge batches carry NO clamp/gate; the <=15-edge tail runs a
// dynamic ceil(rem/4)-step loop with the clamp -> ~28% -> ~6% wasted slots.
// Reduce via xor16+xor32; fused gemm2 slab epilogue.
// ---------------------------------------------------------------------------
__global__ __launch_bounds__(256) void agg1_gemm2_kernel(
    const unsigned short* __restrict__ h, const unsigned* __restrict__ recs,
    const int2* __restrict__ rowrange, const float* __restrict__ dinv,
    const float* __restrict__ b1, const unsigned short* __restrict__ Wf2,
    unsigned short* __restrict__ h2, int n) {
  __shared__ unsigned short tile[16][136];  // +8 pad; 272B row stride
  const int wave = threadIdx.x >> 6;
  const int lane = threadIdx.x & 63;
  const int qt = lane >> 4;        // quarter id 0..3 (edge slot within j)
  const int li = lane & 15;        // cols 8*li .. 8*li+7 (16B per lane)
  const int nbase = blockIdx.x * 16;
  const unsigned* rbase = recs + (size_t)(nbase >> 8) * CAPB;
  const unsigned short* hc = h + li * 8;

  for (int q = 0; q < 4; ++q) {
    const int row = wave * 4 + q;
    const int nid = nbase + row;
    if (nid >= n) break;
    const float di = dinv[nid];
    const int2 rr = rowrange[nid];
    int p = rr.x;
    const int end = rr.y;
    float a0 = 0.f, a1 = 0.f, a2 = 0.f, a3 = 0.f;
    float a4 = 0.f, a5 = 0.f, a6 = 0.f, a7 = 0.f;
    const int nfull = (end - p) >> 4;
    for (int bt = 0; bt < nfull; ++bt) {
#pragma unroll
      for (int j = 0; j < 4; ++j) {
        unsigned r = rbase[p + j * 4 + qt];
        float w = bf_hi(r);
        uint4 u = *(const uint4*)(hc + (size_t)(r & 0xffffu) * 128);
        a0 += bf_lo(u.x) * w;
        a1 += bf_hi(u.x) * w;
        a2 += bf_lo(u.y) * w;
        a3 += bf_hi(u.y) * w;
        a4 += bf_lo(u.z) * w;
        a5 += bf_hi(u.z) * w;
        a6 += bf_lo(u.w) * w;
        a7 += bf_hi(u.w) * w;
      }
      p += 16;
    }
    const int rem = end - p;  // 0..15
    const int jt = (rem + 3) >> 2;
    for (int j = 0; j < jt; ++j) {
      int ei = p + j * 4 + qt;
      int ec = min(ei, end - 1);
      unsigned r = rbase[ec];
      float w = (ei < end) ? bf_hi(r) : 0.f;
      uint4 u = *(const uint4*)(hc + (size_t)(r & 0xffffu) * 128);
      a0 += bf_lo(u.x) * w;
      a1 += bf_hi(u.x) * w;
      a2 += bf_lo(u.y) * w;
      a3 += bf_hi(u.y) * w;
      a4 += bf_lo(u.z) * w;
      a5 += bf_hi(u.z) * w;
      a6 += bf_lo(u.w) * w;
      a7 += bf_hi(u.w) * w;
    }
    // combine quarters (register permutes)
    a0 += __shfl_xor(a0, 16, 64); a0 += __shfl_xor(a0, 32, 64);
    a1 += __shfl_xor(a1, 16, 64); a1 += __shfl_xor(a1, 32, 64);
    a2 += __shfl_xor(a2, 16, 64); a2 += __shfl_xor(a2, 32, 64);
    a3 += __shfl_xor(a3, 16, 64); a3 += __shfl_xor(a3, 32, 64);
    a4 += __shfl_xor(a4, 16, 64); a4 += __shfl_xor(a4, 32, 64);
    a5 += __shfl_xor(a5, 16, 64); a5 += __shfl_xor(a5, 32, 64);
    a6 += __shfl_xor(a6, 16, 64); a6 += __shfl_xor(a6, 32, 64);
    a7 += __shfl_xor(a7, 16, 64); a7 += __shfl_xor(a7, 32, 64);
    if (qt == 0) {
      uint4 u = *(const uint4*)(hc + (size_t)nid * 128);
      float w2 = di * di;
      a0 += bf_lo(u.x) * w2;
      a1 += bf_hi(u.x) * w2;
      a2 += bf_lo(u.y) * w2;
      a3 += bf_hi(u.y) * w2;
      a4 += bf_lo(u.z) * w2;
      a5 += bf_hi(u.z) * w2;
      a6 += bf_lo(u.w) * w2;
      a7 += bf_hi(u.w) * w2;
      float4 bv0 = *(const float4*)(b1 + li * 8);
      float4 bv1 = *(const float4*)(b1 + li * 8 + 4);
      a0 = fmaxf(a0 + bv0.x, 0.f);
      a1 = fmaxf(a1 + bv0.y, 0.f);
      a2 = fmaxf(a2 + bv0.z, 0.f);
      a3 = fmaxf(a3 + bv0.w, 0.f);
      a4 = fmaxf(a4 + bv1.x, 0.f);
      a5 = fmaxf(a5 + bv1.y, 0.f);
      a6 = fmaxf(a6 + bv1.z, 0.f);
      a7 = fmaxf(a7 + bv1.w, 0.f);
      uint4 pk;
      pk.x = ((unsigned)f2bf(a1) << 16) | f2bf(a0);
      pk.y = ((unsigned)f2bf(a3) << 16) | f2bf(a2);
      pk.z = ((unsigned)f2bf(a5) << 16) | f2bf(a4);
      pk.w = ((unsigned)f2bf(a7) << 16) | f2bf(a6);
      *(uint4*)&tile[row][li * 8] = pk;
    }
  }
  __syncthreads();

  const int g = lane >> 4;
  const int m15 = lane & 15;
  f32x4 acc = (f32x4){0.f, 0.f, 0.f, 0.f};
#pragma unroll
  for (int t = 0; t < 4; ++t) {
    bf16x8 af = *(const bf16x8*)&tile[m15][t * 32 + g * 8];
    bf16x8 bf = *(const bf16x8*)(Wf2 + ((size_t)((wave * 4 + t) * 64 + lane)) * 8);
    acc = __builtin_amdgcn_mfma_f32_16x16x32_bf16(af, bf, acc, 0, 0, 0);
  }
#pragma unroll
  for (int r = 0; r < 4; ++r) {
    int row = nbase + g * 4 + r;
    if (row < n) h2[(size_t)row * DOUT + wave * 16 + m15] = f2bf(acc[r]);
  }
}

// ---------------------------------------------------------------------------
// agg2: one wave per node; QUARTER-WAVE gather of 128B h2 rows (16 lanes x
// 8B uint2, 4 cols/lane), 4 edges/j-step. Full batches gate-free + dynamic
// ceil(rem/4)-step tail; fp32 out.
// ---------------------------------------------------------------------------
__global__ __launch_bounds__(256) void aggregate2_kernel(
    const unsigned short* __restrict__ h, const unsigned* __restrict__ recs,
    const int2* __restrict__ rowrange, const float* __restrict__ dinv,
    const float* __restrict__ bias, float* __restrict__ out, int n) {
  const int wave = threadIdx.x >> 6;
  const int lane = threadIdx.x & 63;
  const int qt = lane >> 4;
  const int li = lane & 15;  // cols 4*li .. 4*li+3
  const int nid = blockIdx.x * 4 + wave;
  if (nid >= n) return;

  const unsigned* rbase = recs + (size_t)(nid >> 8) * CAPB;
  const float di = dinv[nid];
  const int2 rr = rowrange[nid];
  int p = rr.x;
  const int end = rr.y;
  const unsigned short* hc = h + li * 4;

  float a0 = 0.f, a1 = 0.f, a2 = 0.f, a3 = 0.f;
  const int nfull = (end - p) >> 4;
  for (int bt = 0; bt < nfull; ++bt) {
#pragma unroll
    for (int j = 0; j < 4; ++j) {
      unsigned r = rbase[p + j * 4 + qt];
      float w = bf_hi(r);
      uint2 u = *(const uint2*)(hc + (size_t)(r & 0xffffu) * 64);
      a0 += bf_lo(u.x) * w;
      a1 += bf_hi(u.x) * w;
      a2 += bf_lo(u.y) * w;
      a3 += bf_hi(u.y) * w;
    }
    p += 16;
  }
  const int rem = end - p;  // 0..15
  const int jt = (rem + 3) >> 2;
  for (int j = 0; j < jt; ++j) {
    int ei = p + j * 4 + qt;
    int ec = min(ei, end - 1);
    unsigned r = rbase[ec];
    float w = (ei < end) ? bf_hi(r) : 0.f;
    uint2 u = *(const uint2*)(hc + (size_t)(r & 0xffffu) * 64);
    a0 += bf_lo(u.x) * w;
    a1 += bf_hi(u.x) * w;
    a2 += bf_lo(u.y) * w;
    a3 += bf_hi(u.y) * w;
  }
  a0 += __shfl_xor(a0, 16, 64); a0 += __shfl_xor(a0, 32, 64);
  a1 += __shfl_xor(a1, 16, 64); a1 += __shfl_xor(a1, 32, 64);
  a2 += __shfl_xor(a2, 16, 64); a2 += __shfl_xor(a2, 32, 64);
  a3 += __shfl_xor(a3, 16, 64); a3 += __shfl_xor(a3, 32, 64);
  if (qt == 0) {
    uint2 u = *(const uint2*)(hc + (size_t)nid * 64);
    float w2 = di * di;
    a0 += bf_lo(u.x) * w2;
    a1 += bf_hi(u.x) * w2;
    a2 += bf_lo(u.y) * w2;
    a3 += bf_hi(u.y) * w2;
    float4 bv = *(const float4*)(bias + li * 4);
    a0 = fmaxf(a0 + bv.x, 0.f);
    a1 = fmaxf(a1 + bv.y, 0.f);
    a2 = fmaxf(a2 + bv.z, 0.f);
    a3 = fmaxf(a3 + bv.w, 0.f);
    *(float4*)(out + (size_t)nid * 64 + li * 4) = make_float4(a0, a1, a2, a3);
  }
}

// ---------------------------------------------------------------------------
extern "C" void kernel_launch(void* const* d_in, const int* in_sizes, int n_in,
                              void* d_out, int out_size, void* d_ws, size_t ws_size,
                              hipStream_t stream) {
  const float* x = (const float*)d_in[0];
  const int* edge = (const int*)d_in[1];
  const float* W1 = (const float*)d_in[2];
  const float* b1 = (const float*)d_in[3];
  const float* W2 = (const float*)d_in[4];
  const float* b2 = (const float*)d_in[5];
  float* out = (float*)d_out;

  const int N = in_sizes[0] / DIN;   // 50000 (< 65536: src fits in u16)
  const int E = in_sizes[1] / 2;
  const int* src = edge;
  const int* dst = edge + E;
  const int NR = (N + 255) >> 8;              // 196 ranges
  const int nbinA = (E + CHUNK - 1) / CHUNK;  // 196
  const int ntiles1 = (N + 63) / 64;          // 782 gemm1 tiles

  char* base = (char*)d_ws;
  size_t off = 0;
  auto carve = [&](size_t bytes) {
    char* p = base + off;
    off += (bytes + 255) & ~(size_t)255;
    return p;
  };
  float* dinv = (float*)carve((size_t)N * 4);
  int2* rowrange = (int2*)carve((size_t)N * 8);
  int* bincursor = (int*)carve(256 * 4);
  unsigned* binbuf = (unsigned*)carve((size_t)NR * CAPB * 4 + CAPB * 4);
  unsigned short* h1 = (unsigned short*)carve((size_t)N * DHID * 2);  // bf16
  unsigned short* h2 = (unsigned short*)carve((size_t)N * DOUT * 2);  // bf16
  unsigned short* Wf1 = (unsigned short*)carve((size_t)DIN * DHID * 2);
  unsigned short* Wf2 = (unsigned short*)carve((size_t)DHID * DOUT * 2);
  unsigned* recs = binbuf;  // binB permutes in-place

  init_kernel<<<13, 256, 0, stream>>>(W1, W2, Wf1, Wf2, bincursor);
  phaseA_kernel<<<nbinA + ntiles1, 256, 0, stream>>>(
      src, dst, bincursor, binbuf, E, nbinA, x, Wf1, h1, N);
  scan_local_kernel<<<NR, 256, 0, stream>>>(binbuf, bincursor, rowrange, dinv, N);
  binB_kernel<<<NR, 256, 0, stream>>>(binbuf, bincursor, rowrange, dinv, N);
  agg1_gemm2_kernel<<<(N + 15) / 16, 256, 0, stream>>>(
      h1, recs, rowrange, dinv, b1, Wf2, h2, N);
  aggregate2_kernel<<<(N + 3) / 4, 256, 0, stream>>>(
      h2, recs, rowrange, dinv, b2, out, N);
}

// Round 18
// 164.942 us; speedup vs baseline: 1.0378x; 1.0378x over previous
//
#include <hip/hip_runtime.h>

#define DIN 128
#define DHID 128
#define DOUT 64
#define CAPB 6144    // bin capacity per 256-node range (mean ~4082, sigma ~64)
#define CHUNK 4096   // edges per binA block
#define EPT (CHUNK / 256)

typedef short bf16x8 __attribute__((ext_vector_type(8)));
typedef float f32x4 __attribute__((ext_vector_type(4)));

// ---- bf16 helpers ---------------------------------------------------------
static __device__ __forceinline__ unsigned short f2bf(float f) {
  union { float f; unsigned u; } v; v.f = f;
  unsigned r = v.u + 0x7fffu + ((v.u >> 16) & 1u);  // round-nearest-even
  return (unsigned short)(r >> 16);
}
static __device__ __forceinline__ float bf_lo(unsigned v) {
  union { unsigned u; float f; } t; t.u = v << 16; return t.f;
}
static __device__ __forceinline__ float bf_hi(unsigned v) {
  union { unsigned u; float f; } t; t.u = v & 0xffff0000u; return t.f;
}

// ---------------------------------------------------------------------------
// init: zero bincursor + frag-order bf16 conversion of W1/W2 (one launch).
// ---------------------------------------------------------------------------
static __device__ __forceinline__ void wcast_body(
    const float* __restrict__ W, unsigned short* __restrict__ Wf,
    int NOUT, int tid) {
  int f = tid >> 6;
  int lane = tid & 63;
  int t = f & 3;
  int nt = f >> 2;
  int kbase = t * 32 + (lane >> 4) * 8;
  int n = nt * 16 + (lane & 15);
#pragma unroll
  for (int j = 0; j < 8; ++j)
    Wf[(size_t)tid * 8 + j] = f2bf(W[(size_t)(kbase + j) * NOUT + n]);
}

__global__ __launch_bounds__(256) void init_kernel(
    const float* __restrict__ W1, const float* __restrict__ W2,
    unsigned short* __restrict__ Wf1, unsigned short* __restrict__ Wf2,
    int* __restrict__ bincursor) {
  const int b = blockIdx.x;
  const int t = threadIdx.x;
  if (b == 0) {
    bincursor[t] = 0;
  } else if (b <= 8) {
    wcast_body(W1, Wf1, DHID, (b - 1) * 256 + t);
  } else {
    wcast_body(W2, Wf2, DOUT, (b - 9) * 256 + t);
  }
}

// ---------------------------------------------------------------------------
// gemm1 tile: 64 rows of C[M,128](bf16) = A[M,128](fp32) * Wf1 (regs).
// ---------------------------------------------------------------------------
static __device__ void gemm1_tile(
    const float* __restrict__ A, const unsigned short* __restrict__ Wf,
    unsigned short* __restrict__ C, int M, int tile) {
  constexpr int NT = DHID / 16;  // 8
  const int lane = threadIdx.x & 63;
  const int wave = threadIdx.x >> 6;
  const int g = lane >> 4;
  const int m15 = lane & 15;

  bf16x8 bfrag[NT * 4];
#pragma unroll
  for (int f = 0; f < NT * 4; ++f)
    bfrag[f] = *(const bf16x8*)(Wf + ((size_t)(f * 64 + lane)) * 8);

  const int rowbase = tile * 64 + wave * 16;
  if (rowbase >= M) return;
  f32x4 acc[NT];
#pragma unroll
  for (int nt = 0; nt < NT; ++nt) acc[nt] = (f32x4){0.f, 0.f, 0.f, 0.f};
  const float* arow = A + (size_t)(rowbase + m15) * 128 + g * 8;
  bf16x8 af[4];
#pragma unroll
  for (int t = 0; t < 4; ++t) {
    float4 a0 = *(const float4*)(arow + t * 32);
    float4 a1 = *(const float4*)(arow + t * 32 + 4);
    bf16x8 f;
    f[0] = (short)f2bf(a0.x); f[1] = (short)f2bf(a0.y);
    f[2] = (short)f2bf(a0.z); f[3] = (short)f2bf(a0.w);
    f[4] = (short)f2bf(a1.x); f[5] = (short)f2bf(a1.y);
    f[6] = (short)f2bf(a1.z); f[7] = (short)f2bf(a1.w);
    af[t] = f;
  }
#pragma unroll
  for (int t = 0; t < 4; ++t)
#pragma unroll
    for (int nt = 0; nt < NT; ++nt)
      acc[nt] = __builtin_amdgcn_mfma_f32_16x16x32_bf16(
          af[t], bfrag[nt * 4 + t], acc[nt], 0, 0, 0);
#pragma unroll
  for (int nt = 0; nt < NT; ++nt)
#pragma unroll
    for (int r = 0; r < 4; ++r) {
      int row = rowbase + g * 4 + r;
      if (row < M)
        C[(size_t)row * DHID + nt * 16 + m15] = f2bf(acc[nt][r]);
    }
}

// ---------------------------------------------------------------------------
// phaseA: blocks [0,nbinA) bin edges by range (LDS, burst writes); blocks
// [nbinA, ...) each run one gemm1 tile (independent -> overlap).
// ---------------------------------------------------------------------------
__global__ __launch_bounds__(256) void phaseA_kernel(
    const int* __restrict__ src, const int* __restrict__ dst,
    int* __restrict__ bincursor, unsigned* __restrict__ binbuf, int E,
    int nbinA, const float* __restrict__ x,
    const unsigned short* __restrict__ Wf1, unsigned short* __restrict__ h1,
    int M) {
  __shared__ int hist[256];
  __shared__ int cnt[256];
  __shared__ int offs[256];
  __shared__ int cur[256];
  __shared__ int gbase[256];
  __shared__ unsigned stage[CHUNK];

  if ((int)blockIdx.x >= nbinA) {
    gemm1_tile(x, Wf1, h1, M, (int)blockIdx.x - nbinA);
    return;
  }

  const int t = threadIdx.x;
  const int base = blockIdx.x * CHUNK;
  const int n = min(CHUNK, E - base);

  hist[t] = 0;
  __syncthreads();

  unsigned rec[EPT];
  int rng[EPT];
#pragma unroll
  for (int j = 0; j < EPT; ++j) {
    int e = base + j * 256 + t;
    rng[j] = -1;
    if (e < E) {
      int d = dst[e];
      int s = src[e];
      int r = d >> 8;
      rng[j] = r;
      rec[j] = (unsigned)s | ((unsigned)(d & 255) << 16) | ((unsigned)r << 24);
      atomicAdd(&hist[r], 1);
    }
  }
  __syncthreads();
  int myc = hist[t];
  cnt[t] = myc;
  __syncthreads();
#pragma unroll
  for (int o = 1; o < 256; o <<= 1) {
    int u = (t >= o) ? hist[t - o] : 0;
    __syncthreads();
    hist[t] += u;
    __syncthreads();
  }
  offs[t] = hist[t] - myc;
  cur[t] = hist[t] - myc;
  __syncthreads();
#pragma unroll
  for (int j = 0; j < EPT; ++j) {
    if (rng[j] >= 0) {
      int pos = atomicAdd(&cur[rng[j]], 1);
      stage[pos] = rec[j];
    }
  }
  __syncthreads();
  int c = cnt[t];
  gbase[t] = c ? atomicAdd(&bincursor[t], c) : 0;
  __syncthreads();
  for (int i = t; i < n; i += 256) {
    unsigned v = stage[i];
    int r = v >> 24;
    int local = i - offs[r];
    int gpos = gbase[r] + local;
    if (gpos < CAPB) binbuf[(size_t)r * CAPB + gpos] = v & 0x00ffffffu;
  }
}

// ---------------------------------------------------------------------------
// scan_local: block b histograms its range's bin segment -> deg, fuses dinv,
// local exclusive scan -> rowrange[i] = (start, end) LOCAL to the range.
// ---------------------------------------------------------------------------
__global__ __launch_bounds__(256) void scan_local_kernel(
    const unsigned* __restrict__ binbuf, const int* __restrict__ bincursor,
    int2* __restrict__ rowrange, float* __restrict__ dinv, int n) {
  __shared__ int deg[256];
  __shared__ int lds[256];
  const int t = threadIdx.x;
  const int b = blockIdx.x;
  deg[t] = 0;
  __syncthreads();
  const int cnt = min(bincursor[b], CAPB);
  const unsigned* seg = binbuf + (size_t)b * CAPB;
  for (int i = t; i < cnt; i += 256) atomicAdd(&deg[(seg[i] >> 16) & 0xff], 1);
  __syncthreads();
  const int i = b * 256 + t;
  int v = deg[t];
  if (i < n) dinv[i] = rsqrtf((float)v + 1.0f);
  lds[t] = v;
  __syncthreads();
#pragma unroll
  for (int o = 1; o < 256; o <<= 1) {
    int u = (t >= o) ? lds[t - o] : 0;
    __syncthreads();
    lds[t] += u;
    __syncthreads();
  }
  if (i < n) rowrange[i] = make_int2(lds[t] - v, lds[t]);
}

// ---------------------------------------------------------------------------
// binB: one block per range; reads its contiguous bin segment, computes
// weights (dinv L2-hot), places recs (src | bf16(w)<<16) via LDS cursors,
// writes back IN-PLACE (all global reads of the segment complete before the
// post-sync writes; saves a 3.2 MB buffer + writeback).
// ---------------------------------------------------------------------------
__global__ __launch_bounds__(256) void binB_kernel(
    unsigned* __restrict__ binbuf, const int* __restrict__ bincursor,
    const int2* __restrict__ rowrange, const float* __restrict__ dinv,
    int n) {
  __shared__ int curs[256];
  __shared__ unsigned stage[CAPB];
  const int t = threadIdx.x;
  const int r = blockIdx.x;
  const int n0 = r * 256;
  curs[t] = (n0 + t < n) ? rowrange[n0 + t].x : 0;
  __syncthreads();
  const int cnt = min(bincursor[r], CAPB);
  unsigned* seg = binbuf + (size_t)r * CAPB;
  for (int i = t; i < cnt; i += 256) {
    unsigned v = seg[i];
    int s = v & 0xffffu;
    int dl = (v >> 16) & 0xff;
    float w = dinv[s] * dinv[n0 + dl];
    int pos = atomicAdd(&curs[dl], 1);
    stage[pos] = (unsigned)s | ((unsigned)f2bf(w) << 16);
  }
  __syncthreads();
  for (int i = t; i < cnt; i += 256) seg[i] = stage[i];
}

// ---------------------------------------------------------------------------
// agg1_gemm2 (round-15 known-good form): block = 16 nodes, wave = 4 nodes.
// QUARTER-WAVE gather: each 16-lane quarter fetches one edge's full 256B h1
// row as uint4 (16B/lane) -> 4 edges per j-step, 4 j-steps per 16-edge
// clamped batch (dup loads = L1 hits). Reduce via xor16+xor32; fused gemm2
// slab epilogue.
// ---------------------------------------------------------------------------
__global__ __launch_bounds__(256) void agg1_gemm2_kernel(
    const unsigned short* __restrict__ h, const unsigned* __restrict__ recs,
    const int2* __restrict__ rowrange, const float* __restrict__ dinv,
    const float* __restrict__ b1, const unsigned short* __restrict__ Wf2,
    unsigned short* __restrict__ h2, int n) {
  __shared__ unsigned short tile[16][136];  // +8 pad; 272B row stride
  const int wave = threadIdx.x >> 6;
  const int lane = threadIdx.x & 63;
  const int qt = lane >> 4;        // quarter id 0..3 (edge slot within j)
  const int li = lane & 15;        // cols 8*li .. 8*li+7 (16B per lane)
  const int nbase = blockIdx.x * 16;
  const unsigned* rbase = recs + (size_t)(nbase >> 8) * CAPB;
  const unsigned short* hc = h + li * 8;

  for (int q = 0; q < 4; ++q) {
    const int row = wave * 4 + q;
    const int nid = nbase + row;
    if (nid >= n) break;
    const float di = dinv[nid];
    const int2 rr = rowrange[nid];
    const int p0 = rr.x;
    const int end = rr.y;
    const int d = end - p0;
    const int last = (d > 0) ? (end - 1) : p0;
    float a0 = 0.f, a1 = 0.f, a2 = 0.f, a3 = 0.f;
    float a4 = 0.f, a5 = 0.f, a6 = 0.f, a7 = 0.f;
    const int nb = (d + 15) >> 4;
    for (int bt = 0; bt < nb; ++bt) {
      const int pb = p0 + (bt << 4) + qt;
#pragma unroll
      for (int j = 0; j < 4; ++j) {
        int ei = pb + j * 4;
        int ec = min(ei, last);
        unsigned r = rbase[ec];
        float w = (ei < end) ? bf_hi(r) : 0.f;
        uint4 u = *(const uint4*)(hc + (size_t)(r & 0xffffu) * 128);
        a0 += bf_lo(u.x) * w;
        a1 += bf_hi(u.x) * w;
        a2 += bf_lo(u.y) * w;
        a3 += bf_hi(u.y) * w;
        a4 += bf_lo(u.z) * w;
        a5 += bf_hi(u.z) * w;
        a6 += bf_lo(u.w) * w;
        a7 += bf_hi(u.w) * w;
      }
    }
    // combine quarters (register permutes)
    a0 += __shfl_xor(a0, 16, 64); a0 += __shfl_xor(a0, 32, 64);
    a1 += __shfl_xor(a1, 16, 64); a1 += __shfl_xor(a1, 32, 64);
    a2 += __shfl_xor(a2, 16, 64); a2 += __shfl_xor(a2, 32, 64);
    a3 += __shfl_xor(a3, 16, 64); a3 += __shfl_xor(a3, 32, 64);
    a4 += __shfl_xor(a4, 16, 64); a4 += __shfl_xor(a4, 32, 64);
    a5 += __shfl_xor(a5, 16, 64); a5 += __shfl_xor(a5, 32, 64);
    a6 += __shfl_xor(a6, 16, 64); a6 += __shfl_xor(a6, 32, 64);
    a7 += __shfl_xor(a7, 16, 64); a7 += __shfl_xor(a7, 32, 64);
    if (qt == 0) {
      uint4 u = *(const uint4*)(hc + (size_t)nid * 128);
      float w2 = di * di;
      a0 += bf_lo(u.x) * w2;
      a1 += bf_hi(u.x) * w2;
      a2 += bf_lo(u.y) * w2;
      a3 += bf_hi(u.y) * w2;
      a4 += bf_lo(u.z) * w2;
      a5 += bf_hi(u.z) * w2;
      a6 += bf_lo(u.w) * w2;
      a7 += bf_hi(u.w) * w2;
      float4 bv0 = *(const float4*)(b1 + li * 8);
      float4 bv1 = *(const float4*)(b1 + li * 8 + 4);
      a0 = fmaxf(a0 + bv0.x, 0.f);
      a1 = fmaxf(a1 + bv0.y, 0.f);
      a2 = fmaxf(a2 + bv0.z, 0.f);
      a3 = fmaxf(a3 + bv0.w, 0.f);
      a4 = fmaxf(a4 + bv1.x, 0.f);
      a5 = fmaxf(a5 + bv1.y, 0.f);
      a6 = fmaxf(a6 + bv1.z, 0.f);
      a7 = fmaxf(a7 + bv1.w, 0.f);
      uint4 pk;
      pk.x = ((unsigned)f2bf(a1) << 16) | f2bf(a0);
      pk.y = ((unsigned)f2bf(a3) << 16) | f2bf(a2);
      pk.z = ((unsigned)f2bf(a5) << 16) | f2bf(a4);
      pk.w = ((unsigned)f2bf(a7) << 16) | f2bf(a6);
      *(uint4*)&tile[row][li * 8] = pk;
    }
  }
  __syncthreads();

  const int g = lane >> 4;
  const int m15 = lane & 15;
  f32x4 acc = (f32x4){0.f, 0.f, 0.f, 0.f};
#pragma unroll
  for (int t = 0; t < 4; ++t) {
    bf16x8 af = *(const bf16x8*)&tile[m15][t * 32 + g * 8];
    bf16x8 bf = *(const bf16x8*)(Wf2 + ((size_t)((wave * 4 + t) * 64 + lane)) * 8);
    acc = __builtin_amdgcn_mfma_f32_16x16x32_bf16(af, bf, acc, 0, 0, 0);
  }
#pragma unroll
  for (int r = 0; r < 4; ++r) {
    int row = nbase + g * 4 + r;
    if (row < n) h2[(size_t)row * DOUT + wave * 16 + m15] = f2bf(acc[r]);
  }
}

// ---------------------------------------------------------------------------
// agg2 (round-15 known-good form): one wave per node; QUARTER-WAVE gather of
// 128B h2 rows (16 lanes x 8B uint2, 4 cols/lane), clamped batches; fp32 out.
// ---------------------------------------------------------------------------
__global__ __launch_bounds__(256) void aggregate2_kernel(
    const unsigned short* __restrict__ h, const unsigned* __restrict__ recs,
    const int2* __restrict__ rowrange, const float* __restrict__ dinv,
    const float* __restrict__ bias, float* __restrict__ out, int n) {
  const int wave = threadIdx.x >> 6;
  const int lane = threadIdx.x & 63;
  const int qt = lane >> 4;
  const int li = lane & 15;  // cols 4*li .. 4*li+3
  const int nid = blockIdx.x * 4 + wave;
  if (nid >= n) return;

  const unsigned* rbase = recs + (size_t)(nid >> 8) * CAPB;
  const float di = dinv[nid];
  const int2 rr = rowrange[nid];
  const int p0 = rr.x;
  const int end = rr.y;
  const int d = end - p0;
  const int last = (d > 0) ? (end - 1) : p0;
  const unsigned short* hc = h + li * 4;

  float a0 = 0.f, a1 = 0.f, a2 = 0.f, a3 = 0.f;
  const int nb = (d + 15) >> 4;
  for (int bt = 0; bt < nb; ++bt) {
    const int pb = p0 + (bt << 4) + qt;
#pragma unroll
    for (int j = 0; j < 4; ++j) {
      int ei = pb + j * 4;
      int ec = min(ei, last);
      unsigned r = rbase[ec];
      float w = (ei < end) ? bf_hi(r) : 0.f;
      uint2 u = *(const uint2*)(hc + (size_t)(r & 0xffffu) * 64);
      a0 += bf_lo(u.x) * w;
      a1 += bf_hi(u.x) * w;
      a2 += bf_lo(u.y) * w;
      a3 += bf_hi(u.y) * w;
    }
  }
  a0 += __shfl_xor(a0, 16, 64); a0 += __shfl_xor(a0, 32, 64);
  a1 += __shfl_xor(a1, 16, 64); a1 += __shfl_xor(a1, 32, 64);
  a2 += __shfl_xor(a2, 16, 64); a2 += __shfl_xor(a2, 32, 64);
  a3 += __shfl_xor(a3, 16, 64); a3 += __shfl_xor(a3, 32, 64);
  if (qt == 0) {
    uint2 u = *(const uint2*)(hc + (size_t)nid * 64);
    float w2 = di * di;
    a0 += bf_lo(u.x) * w2;
    a1 += bf_hi(u.x) * w2;
    a2 += bf_lo(u.y) * w2;
    a3 += bf_hi(u.y) * w2;
    float4 bv = *(const float4*)(bias + li * 4);
    a0 = fmaxf(a0 + bv.x, 0.f);
    a1 = fmaxf(a1 + bv.y, 0.f);
    a2 = fmaxf(a2 + bv.z, 0.f);
    a3 = fmaxf(a3 + bv.w, 0.f);
    *(float4*)(out + (size_t)nid * 64 + li * 4) = make_float4(a0, a1, a2, a3);
  }
}

// ---------------------------------------------------------------------------
extern "C" void kernel_launch(void* const* d_in, const int* in_sizes, int n_in,
                              void* d_out, int out_size, void* d_ws, size_t ws_size,
                              hipStream_t stream) {
  const float* x = (const float*)d_in[0];
  const int* edge = (const int*)d_in[1];
  const float* W1 = (const float*)d_in[2];
  const float* b1 = (const float*)d_in[3];
  const float* W2 = (const float*)d_in[4];
  const float* b2 = (const float*)d_in[5];
  float* out = (float*)d_out;

  const int N = in_sizes[0] / DIN;   // 50000 (< 65536: src fits in u16)
  const int E = in_sizes[1] / 2;
  const int* src = edge;
  const int* dst = edge + E;
  const int NR = (N + 255) >> 8;              // 196 ranges
  const int nbinA = (E + CHUNK - 1) / CHUNK;  // 196
  const int ntiles1 = (N + 63) / 64;          // 782 gemm1 tiles

  char* base = (char*)d_ws;
  size_t off = 0;
  auto carve = [&](size_t bytes) {
    char* p = base + off;
    off += (bytes + 255) & ~(size_t)255;
    return p;
  };
  float* dinv = (float*)carve((size_t)N * 4);
  int2* rowrange = (int2*)carve((size_t)N * 8);
  int* bincursor = (int*)carve(256 * 4);
  unsigned* binbuf = (unsigned*)carve((size_t)NR * CAPB * 4 + CAPB * 4);
  unsigned short* h1 = (unsigned short*)carve((size_t)N * DHID * 2);  // bf16
  unsigned short* h2 = (unsigned short*)carve((size_t)N * DOUT * 2);  // bf16
  unsigned short* Wf1 = (unsigned short*)carve((size_t)DIN * DHID * 2);
  unsigned short* Wf2 = (unsigned short*)carve((size_t)DHID * DOUT * 2);
  unsigned* recs = binbuf;  // binB permutes in-place

  init_kernel<<<13, 256, 0, stream>>>(W1, W2, Wf1, Wf2, bincursor);
  phaseA_kernel<<<nbinA + ntiles1, 256, 0, stream>>>(
      src, dst, bincursor, binbuf, E, nbinA, x, Wf1, h1, N);
  scan_local_kernel<<<NR, 256, 0, stream>>>(binbuf, bincursor, rowrange, dinv, N);
  binB_kernel<<<NR, 256, 0, stream>>>(binbuf, bincursor, rowrange, dinv, N);
  agg1_gemm2_kernel<<<(N + 15) / 16, 256, 0, stream>>>(
      h1, recs, rowrange, dinv, b1, Wf2, h2, N);
  aggregate2_kernel<<<(N + 3) / 4, 256, 0, stream>>>(
      h2, recs, rowrange, dinv, b2, out, N);
}

// Round 19
// 164.676 us; speedup vs baseline: 1.0395x; 1.0016x over previous
//
#include <hip/hip_runtime.h>

#define DIN 128
#define DHID 128
#define DOUT 64
#define CAPB 6144    // bin capacity per 256-node range (mean ~4082, sigma ~64)
#define CHUNK 4096   // edges per binA block
#define EPT (CHUNK / 256)

typedef short bf16x8 __attribute__((ext_vector_type(8)));
typedef float f32x4 __attribute__((ext_vector_type(4)));

// ---- bf16 helpers ---------------------------------------------------------
static __device__ __forceinline__ unsigned short f2bf(float f) {
  union { float f; unsigned u; } v; v.f = f;
  unsigned r = v.u + 0x7fffu + ((v.u >> 16) & 1u);  // round-nearest-even
  return (unsigned short)(r >> 16);
}
static __device__ __forceinline__ float bf_lo(unsigned v) {
  union { unsigned u; float f; } t; t.u = v << 16; return t.f;
}
static __device__ __forceinline__ float bf_hi(unsigned v) {
  union { unsigned u; float f; } t; t.u = v & 0xffff0000u; return t.f;
}

// ---------------------------------------------------------------------------
// init: zero bincursor + frag-order bf16 conversion of W1/W2 (one launch).
// ---------------------------------------------------------------------------
static __device__ __forceinline__ void wcast_body(
    const float* __restrict__ W, unsigned short* __restrict__ Wf,
    int NOUT, int tid) {
  int f = tid >> 6;
  int lane = tid & 63;
  int t = f & 3;
  int nt = f >> 2;
  int kbase = t * 32 + (lane >> 4) * 8;
  int n = nt * 16 + (lane & 15);
#pragma unroll
  for (int j = 0; j < 8; ++j)
    Wf[(size_t)tid * 8 + j] = f2bf(W[(size_t)(kbase + j) * NOUT + n]);
}

__global__ __launch_bounds__(256) void init_kernel(
    const float* __restrict__ W1, const float* __restrict__ W2,
    unsigned short* __restrict__ Wf1, unsigned short* __restrict__ Wf2,
    int* __restrict__ bincursor) {
  const int b = blockIdx.x;
  const int t = threadIdx.x;
  if (b == 0) {
    bincursor[t] = 0;
  } else if (b <= 8) {
    wcast_body(W1, Wf1, DHID, (b - 1) * 256 + t);
  } else {
    wcast_body(W2, Wf2, DOUT, (b - 9) * 256 + t);
  }
}

// ---------------------------------------------------------------------------
// gemm1 tile: 64 rows of C[M,128](bf16) = A[M,128](fp32) * Wf1 (regs).
// ---------------------------------------------------------------------------
static __device__ void gemm1_tile(
    const float* __restrict__ A, const unsigned short* __restrict__ Wf,
    unsigned short* __restrict__ C, int M, int tile) {
  constexpr int NT = DHID / 16;  // 8
  const int lane = threadIdx.x & 63;
  const int wave = threadIdx.x >> 6;
  const int g = lane >> 4;
  const int m15 = lane & 15;

  bf16x8 bfrag[NT * 4];
#pragma unroll
  for (int f = 0; f < NT * 4; ++f)
    bfrag[f] = *(const bf16x8*)(Wf + ((size_t)(f * 64 + lane)) * 8);

  const int rowbase = tile * 64 + wave * 16;
  if (rowbase >= M) return;
  f32x4 acc[NT];
#pragma unroll
  for (int nt = 0; nt < NT; ++nt) acc[nt] = (f32x4){0.f, 0.f, 0.f, 0.f};
  const float* arow = A + (size_t)(rowbase + m15) * 128 + g * 8;
  bf16x8 af[4];
#pragma unroll
  for (int t = 0; t < 4; ++t) {
    float4 a0 = *(const float4*)(arow + t * 32);
    float4 a1 = *(const float4*)(arow + t * 32 + 4);
    bf16x8 f;
    f[0] = (short)f2bf(a0.x); f[1] = (short)f2bf(a0.y);
    f[2] = (short)f2bf(a0.z); f[3] = (short)f2bf(a0.w);
    f[4] = (short)f2bf(a1.x); f[5] = (short)f2bf(a1.y);
    f[6] = (short)f2bf(a1.z); f[7] = (short)f2bf(a1.w);
    af[t] = f;
  }
#pragma unroll
  for (int t = 0; t < 4; ++t)
#pragma unroll
    for (int nt = 0; nt < NT; ++nt)
      acc[nt] = __builtin_amdgcn_mfma_f32_16x16x32_bf16(
          af[t], bfrag[nt * 4 + t], acc[nt], 0, 0, 0);
#pragma unroll
  for (int nt = 0; nt < NT; ++nt)
#pragma unroll
    for (int r = 0; r < 4; ++r) {
      int row = rowbase + g * 4 + r;
      if (row < M)
        C[(size_t)row * DHID + nt * 16 + m15] = f2bf(acc[nt][r]);
    }
}

// ---------------------------------------------------------------------------
// phaseA: blocks [0,nbinA) bin edges by range (LDS, burst writes); blocks
// [nbinA, ...) each run one gemm1 tile (independent -> overlap).
// ---------------------------------------------------------------------------
__global__ __launch_bounds__(256) void phaseA_kernel(
    const int* __restrict__ src, const int* __restrict__ dst,
    int* __restrict__ bincursor, unsigned* __restrict__ binbuf, int E,
    int nbinA, const float* __restrict__ x,
    const unsigned short* __restrict__ Wf1, unsigned short* __restrict__ h1,
    int M) {
  __shared__ int hist[256];
  __shared__ int cnt[256];
  __shared__ int offs[256];
  __shared__ int cur[256];
  __shared__ int gbase[256];
  __shared__ unsigned stage[CHUNK];

  if ((int)blockIdx.x >= nbinA) {
    gemm1_tile(x, Wf1, h1, M, (int)blockIdx.x - nbinA);
    return;
  }

  const int t = threadIdx.x;
  const int base = blockIdx.x * CHUNK;
  const int n = min(CHUNK, E - base);

  hist[t] = 0;
  __syncthreads();

  unsigned rec[EPT];
  int rng[EPT];
#pragma unroll
  for (int j = 0; j < EPT; ++j) {
    int e = base + j * 256 + t;
    rng[j] = -1;
    if (e < E) {
      int d = dst[e];
      int s = src[e];
      int r = d >> 8;
      rng[j] = r;
      rec[j] = (unsigned)s | ((unsigned)(d & 255) << 16) | ((unsigned)r << 24);
      atomicAdd(&hist[r], 1);
    }
  }
  __syncthreads();
  int myc = hist[t];
  cnt[t] = myc;
  __syncthreads();
#pragma unroll
  for (int o = 1; o < 256; o <<= 1) {
    int u = (t >= o) ? hist[t - o] : 0;
    __syncthreads();
    hist[t] += u;
    __syncthreads();
  }
  offs[t] = hist[t] - myc;
  cur[t] = hist[t] - myc;
  __syncthreads();
#pragma unroll
  for (int j = 0; j < EPT; ++j) {
    if (rng[j] >= 0) {
      int pos = atomicAdd(&cur[rng[j]], 1);
      stage[pos] = rec[j];
    }
  }
  __syncthreads();
  int c = cnt[t];
  gbase[t] = c ? atomicAdd(&bincursor[t], c) : 0;
  __syncthreads();
  for (int i = t; i < n; i += 256) {
    unsigned v = stage[i];
    int r = v >> 24;
    int local = i - offs[r];
    int gpos = gbase[r] + local;
    if (gpos < CAPB) binbuf[(size_t)r * CAPB + gpos] = v & 0x00ffffffu;
  }
}

// ---------------------------------------------------------------------------
// scan_local: block b histograms its range's bin segment -> deg, fuses dinv,
// local exclusive scan -> rowrange[i] = (start, end) LOCAL to the range.
// ---------------------------------------------------------------------------
__global__ __launch_bounds__(256) void scan_local_kernel(
    const unsigned* __restrict__ binbuf, const int* __restrict__ bincursor,
    int2* __restrict__ rowrange, float* __restrict__ dinv, int n) {
  __shared__ int deg[256];
  __shared__ int lds[256];
  const int t = threadIdx.x;
  const int b = blockIdx.x;
  deg[t] = 0;
  __syncthreads();
  const int cnt = min(bincursor[b], CAPB);
  const unsigned* seg = binbuf + (size_t)b * CAPB;
  for (int i = t; i < cnt; i += 256) atomicAdd(&deg[(seg[i] >> 16) & 0xff], 1);
  __syncthreads();
  const int i = b * 256 + t;
  int v = deg[t];
  if (i < n) dinv[i] = rsqrtf((float)v + 1.0f);
  lds[t] = v;
  __syncthreads();
#pragma unroll
  for (int o = 1; o < 256; o <<= 1) {
    int u = (t >= o) ? lds[t - o] : 0;
    __syncthreads();
    lds[t] += u;
    __syncthreads();
  }
  if (i < n) rowrange[i] = make_int2(lds[t] - v, lds[t]);
}

// ---------------------------------------------------------------------------
// binB: one block per range; reads its contiguous bin segment, computes
// weights (dinv L2-hot), places recs (src | bf16(w)<<16) via LDS cursors,
// writes back IN-PLACE.
// ---------------------------------------------------------------------------
__global__ __launch_bounds__(256) void binB_kernel(
    unsigned* __restrict__ binbuf, const int* __restrict__ bincursor,
    const int2* __restrict__ rowrange, const float* __restrict__ dinv,
    int n) {
  __shared__ int curs[256];
  __shared__ unsigned stage[CAPB];
  const int t = threadIdx.x;
  const int r = blockIdx.x;
  const int n0 = r * 256;
  curs[t] = (n0 + t < n) ? rowrange[n0 + t].x : 0;
  __syncthreads();
  const int cnt = min(bincursor[r], CAPB);
  unsigned* seg = binbuf + (size_t)r * CAPB;
  for (int i = t; i < cnt; i += 256) {
    unsigned v = seg[i];
    int s = v & 0xffffu;
    int dl = (v >> 16) & 0xff;
    float w = dinv[s] * dinv[n0 + dl];
    int pos = atomicAdd(&curs[dl], 1);
    stage[pos] = (unsigned)s | ((unsigned)f2bf(w) << 16);
  }
  __syncthreads();
  for (int i = t; i < cnt; i += 256) seg[i] = stage[i];
}

// ---------------------------------------------------------------------------
// agg1_gemm2 (round-15 form + max-occupancy hint): block = 16 nodes, wave =
// 4 nodes. QUARTER-WAVE gather: each 16-lane quarter fetches one edge's full
// 256B h1 row as uint4 -> 4 edges/j-step, clamped batches (dup loads = L1
// hits). __launch_bounds__(256,8) requests 32 waves/CU residency (VGPR cap
// 64; kernel uses ~40) for more outstanding gathers.
// ---------------------------------------------------------------------------
__global__ __launch_bounds__(256, 8) void agg1_gemm2_kernel(
    const unsigned short* __restrict__ h, const unsigned* __restrict__ recs,
    const int2* __restrict__ rowrange, const float* __restrict__ dinv,
    const float* __restrict__ b1, const unsigned short* __restrict__ Wf2,
    unsigned short* __restrict__ h2, int n) {
  __shared__ unsigned short tile[16][136];  // +8 pad; 272B row stride
  const int wave = threadIdx.x >> 6;
  const int lane = threadIdx.x & 63;
  const int qt = lane >> 4;        // quarter id 0..3 (edge slot within j)
  const int li = lane & 15;        // cols 8*li .. 8*li+7 (16B per lane)
  const int nbase = blockIdx.x * 16;
  const unsigned* rbase = recs + (size_t)(nbase >> 8) * CAPB;
  const unsigned short* hc = h + li * 8;

  for (int q = 0; q < 4; ++q) {
    const int row = wave * 4 + q;
    const int nid = nbase + row;
    if (nid >= n) break;
    const float di = dinv[nid];
    const int2 rr = rowrange[nid];
    const int p0 = rr.x;
    const int end = rr.y;
    const int d = end - p0;
    const int last = (d > 0) ? (end - 1) : p0;
    float a0 = 0.f, a1 = 0.f, a2 = 0.f, a3 = 0.f;
    float a4 = 0.f, a5 = 0.f, a6 = 0.f, a7 = 0.f;
    const int nb = (d + 15) >> 4;
    for (int bt = 0; bt < nb; ++bt) {
      const int pb = p0 + (bt << 4) + qt;
#pragma unroll
      for (int j = 0; j < 4; ++j) {
        int ei = pb + j * 4;
        int ec = min(ei, last);
        unsigned r = rbase[ec];
        float w = (ei < end) ? bf_hi(r) : 0.f;
        uint4 u = *(const uint4*)(hc + (size_t)(r & 0xffffu) * 128);
        a0 += bf_lo(u.x) * w;
        a1 += bf_hi(u.x) * w;
        a2 += bf_lo(u.y) * w;
        a3 += bf_hi(u.y) * w;
        a4 += bf_lo(u.z) * w;
        a5 += bf_hi(u.z) * w;
        a6 += bf_lo(u.w) * w;
        a7 += bf_hi(u.w) * w;
      }
    }
    // combine quarters (register permutes)
    a0 += __shfl_xor(a0, 16, 64); a0 += __shfl_xor(a0, 32, 64);
    a1 += __shfl_xor(a1, 16, 64); a1 += __shfl_xor(a1, 32, 64);
    a2 += __shfl_xor(a2, 16, 64); a2 += __shfl_xor(a2, 32, 64);
    a3 += __shfl_xor(a3, 16, 64); a3 += __shfl_xor(a3, 32, 64);
    a4 += __shfl_xor(a4, 16, 64); a4 += __shfl_xor(a4, 32, 64);
    a5 += __shfl_xor(a5, 16, 64); a5 += __shfl_xor(a5, 32, 64);
    a6 += __shfl_xor(a6, 16, 64); a6 += __shfl_xor(a6, 32, 64);
    a7 += __shfl_xor(a7, 16, 64); a7 += __shfl_xor(a7, 32, 64);
    if (qt == 0) {
      uint4 u = *(const uint4*)(hc + (size_t)nid * 128);
      float w2 = di * di;
      a0 += bf_lo(u.x) * w2;
      a1 += bf_hi(u.x) * w2;
      a2 += bf_lo(u.y) * w2;
      a3 += bf_hi(u.y) * w2;
      a4 += bf_lo(u.z) * w2;
      a5 += bf_hi(u.z) * w2;
      a6 += bf_lo(u.w) * w2;
      a7 += bf_hi(u.w) * w2;
      float4 bv0 = *(const float4*)(b1 + li * 8);
      float4 bv1 = *(const float4*)(b1 + li * 8 + 4);
      a0 = fmaxf(a0 + bv0.x, 0.f);
      a1 = fmaxf(a1 + bv0.y, 0.f);
      a2 = fmaxf(a2 + bv0.z, 0.f);
      a3 = fmaxf(a3 + bv0.w, 0.f);
      a4 = fmaxf(a4 + bv1.x, 0.f);
      a5 = fmaxf(a5 + bv1.y, 0.f);
      a6 = fmaxf(a6 + bv1.z, 0.f);
      a7 = fmaxf(a7 + bv1.w, 0.f);
      uint4 pk;
      pk.x = ((unsigned)f2bf(a1) << 16) | f2bf(a0);
      pk.y = ((unsigned)f2bf(a3) << 16) | f2bf(a2);
      pk.z = ((unsigned)f2bf(a5) << 16) | f2bf(a4);
      pk.w = ((unsigned)f2bf(a7) << 16) | f2bf(a6);
      *(uint4*)&tile[row][li * 8] = pk;
    }
  }
  __syncthreads();

  const int g = lane >> 4;
  const int m15 = lane & 15;
  f32x4 acc = (f32x4){0.f, 0.f, 0.f, 0.f};
#pragma unroll
  for (int t = 0; t < 4; ++t) {
    bf16x8 af = *(const bf16x8*)&tile[m15][t * 32 + g * 8];
    bf16x8 bf = *(const bf16x8*)(Wf2 + ((size_t)((wave * 4 + t) * 64 + lane)) * 8);
    acc = __builtin_amdgcn_mfma_f32_16x16x32_bf16(af, bf, acc, 0, 0, 0);
  }
#pragma unroll
  for (int r = 0; r < 4; ++r) {
    int row = nbase + g * 4 + r;
    if (row < n) h2[(size_t)row * DOUT + wave * 16 + m15] = f2bf(acc[r]);
  }
}

// ---------------------------------------------------------------------------
// agg2 (round-15 form + max-occupancy hint): one wave per node; QUARTER-WAVE
// gather of 128B h2 rows (16 lanes x 8B uint2), clamped batches; fp32 out.
// ---------------------------------------------------------------------------
__global__ __launch_bounds__(256, 8) void aggregate2_kernel(
    const unsigned short* __restrict__ h, const unsigned* __restrict__ recs,
    const int2* __restrict__ rowrange, const float* __restrict__ dinv,
    const float* __restrict__ bias, float* __restrict__ out, int n) {
  const int wave = threadIdx.x >> 6;
  const int lane = threadIdx.x & 63;
  const int qt = lane >> 4;
  const int li = lane & 15;  // cols 4*li .. 4*li+3
  const int nid = blockIdx.x * 4 + wave;
  if (nid >= n) return;

  const unsigned* rbase = recs + (size_t)(nid >> 8) * CAPB;
  const float di = dinv[nid];
  const int2 rr = rowrange[nid];
  const int p0 = rr.x;
  const int end = rr.y;
  const int d = end - p0;
  const int last = (d > 0) ? (end - 1) : p0;
  const unsigned short* hc = h + li * 4;

  float a0 = 0.f, a1 = 0.f, a2 = 0.f, a3 = 0.f;
  const int nb = (d + 15) >> 4;
  for (int bt = 0; bt < nb; ++bt) {
    const int pb = p0 + (bt << 4) + qt;
#pragma unroll
    for (int j = 0; j < 4; ++j) {
      int ei = pb + j * 4;
      int ec = min(ei, last);
      unsigned r = rbase[ec];
      float w = (ei < end) ? bf_hi(r) : 0.f;
      uint2 u = *(const uint2*)(hc + (size_t)(r & 0xffffu) * 64);
      a0 += bf_lo(u.x) * w;
      a1 += bf_hi(u.x) * w;
      a2 += bf_lo(u.y) * w;
      a3 += bf_hi(u.y) * w;
    }
  }
  a0 += __shfl_xor(a0, 16, 64); a0 += __shfl_xor(a0, 32, 64);
  a1 += __shfl_xor(a1, 16, 64); a1 += __shfl_xor(a1, 32, 64);
  a2 += __shfl_xor(a2, 16, 64); a2 += __shfl_xor(a2, 32, 64);
  a3 += __shfl_xor(a3, 16, 64); a3 += __shfl_xor(a3, 32, 64);
  if (qt == 0) {
    uint2 u = *(const uint2*)(hc + (size_t)nid * 64);
    float w2 = di * di;
    a0 += bf_lo(u.x) * w2;
    a1 += bf_hi(u.x) * w2;
    a2 += bf_lo(u.y) * w2;
    a3 += bf_hi(u.y) * w2;
    float4 bv = *(const float4*)(bias + li * 4);
    a0 = fmaxf(a0 + bv.x, 0.f);
    a1 = fmaxf(a1 + bv.y, 0.f);
    a2 = fmaxf(a2 + bv.z, 0.f);
    a3 = fmaxf(a3 + bv.w, 0.f);
    *(float4*)(out + (size_t)nid * 64 + li * 4) = make_float4(a0, a1, a2, a3);
  }
}

// ---------------------------------------------------------------------------
extern "C" void kernel_launch(void* const* d_in, const int* in_sizes, int n_in,
                              void* d_out, int out_size, void* d_ws, size_t ws_size,
                              hipStream_t stream) {
  const float* x = (const float*)d_in[0];
  const int* edge = (const int*)d_in[1];
  const float* W1 = (const float*)d_in[2];
  const float* b1 = (const float*)d_in[3];
  const float* W2 = (const float*)d_in[4];
  const float* b2 = (const float*)d_in[5];
  float* out = (float*)d_out;

  const int N = in_sizes[0] / DIN;   // 50000 (< 65536: src fits in u16)
  const int E = in_sizes[1] / 2;
  const int* src = edge;
  const int* dst = edge + E;
  const int NR = (N + 255) >> 8;              // 196 ranges
  const int nbinA = (E + CHUNK - 1) / CHUNK;  // 196
  const int ntiles1 = (N + 63) / 64;          // 782 gemm1 tiles

  char* base = (char*)d_ws;
  size_t off = 0;
  auto carve = [&](size_t bytes) {
    char* p = base + off;
    off += (bytes + 255) & ~(size_t)255;
    return p;
  };
  float* dinv = (float*)carve((size_t)N * 4);
  int2* rowrange = (int2*)carve((size_t)N * 8);
  int* bincursor = (int*)carve(256 * 4);
  unsigned* binbuf = (unsigned*)carve((size_t)NR * CAPB * 4 + CAPB * 4);
  unsigned short* h1 = (unsigned short*)carve((size_t)N * DHID * 2);  // bf16
  unsigned short* h2 = (unsigned short*)carve((size_t)N * DOUT * 2);  // bf16
  unsigned short* Wf1 = (unsigned short*)carve((size_t)DIN * DHID * 2);
  unsigned short* Wf2 = (unsigned short*)carve((size_t)DHID * DOUT * 2);
  unsigned* recs = binbuf;  // binB permutes in-place

  init_kernel<<<13, 256, 0, stream>>>(W1, W2, Wf1, Wf2, bincursor);
  phaseA_kernel<<<nbinA + ntiles1, 256, 0, stream>>>(
      src, dst, bincursor, binbuf, E, nbinA, x, Wf1, h1, N);
  scan_local_kernel<<<NR, 256, 0, stream>>>(binbuf, bincursor, rowrange, dinv, N);
  binB_kernel<<<NR, 256, 0, stream>>>(binbuf, bincursor, rowrange, dinv, N);
  agg1_gemm2_kernel<<<(N + 15) / 16, 256, 0, stream>>>(
      h1, recs, rowrange, dinv, b1, Wf2, h2, N);
  aggregate2_kernel<<<(N + 3) / 4, 256, 0, stream>>>(
      h2, recs, rowrange, dinv, b2, out, N);
}